// Round 13
// baseline (20.755 us; speedup 1.0000x reference)
//
#include <hip/hip_runtime.h>
#include <hip/hip_bf16.h>

typedef _Float16 f16;
typedef f16 f16x2 __attribute__((ext_vector_type(2)));
typedef f16 f16x4 __attribute__((ext_vector_type(4)));
typedef f16 f16x8 __attribute__((ext_vector_type(8)));
typedef float f32x4 __attribute__((ext_vector_type(4)));
typedef float f32x16 __attribute__((ext_vector_type(16)));

constexpr int B_  = 4;
constexpr int H_  = 128;
constexpr int W_  = 128;
constexpr int C_  = 64;
constexpr int NH_ = 4;
constexpr int D_  = 16;
constexpr int KK_ = 25;

constexpr int TW_  = 8, TH_ = 8;
constexpr int HWID = 12, HHEI = 12;
constexpr int NPX  = HHEI * HWID;          // 144 halo pixels
// LDS layout (R8/R11/R12 proven):
//   [0    , 18432) abuf  [144][64] f16, chunk-XOR swizzled; staged ref -> r in-place
//   [18432, 26624) mabuf [64][64]  f16; staged main -> q in-place
//   [0    , 27648) xbuf  f32 prob exchange (aliases the above, fenced)
//   [27648, 31744) msbuf [2][4][64] float2 (m,s)
constexpr int MOFF  = NPX * 64 * 2;        // 18432
constexpr int MSOFF = 27648;
constexpr int SMEM  = 31744;               // <= 40960 -> 4 blocks/CU (wave cap)
constexpr int PSTRIDE = KK_ + 2;           // 27
constexpr int PSLAB   = 64 * PSTRIDE;      // 1728 f32

#if __has_builtin(__builtin_amdgcn_fdot2)
#define FDOT2(a, b, c) __builtin_amdgcn_fdot2((a), (b), (c), false)
#else
#define FDOT2(a, b, c) fmaf((float)(a)[1], (float)(b)[1], fmaf((float)(a)[0], (float)(b)[0], (c)))
#endif

__device__ __forceinline__ int div12(int x) { return (x * 171) >> 11; }  // exact for 0..143

__global__ __launch_bounds__(512, 8) void rl8mh13(
    const float* __restrict__ mainp, const float* __restrict__ refp,
    const float* __restrict__ wmain, const float* __restrict__ wref,
    float* __restrict__ out)
{
    __shared__ __align__(16) unsigned char smraw[SMEM];
    f16*    abuf  = (f16*)smraw;             // staged ref halo -> rbuf in-place
    f16*    mabuf = (f16*)(smraw + MOFF);    // staged main     -> qbuf in-place
    float*  xbuf  = (float*)smraw;
    float2* msbuf = (float2*)(smraw + MSOFF);

    const int tid = threadIdx.x;
    const int l   = tid & 63;
    const int wid = __builtin_amdgcn_readfirstlane(tid >> 6);  // 0..7
    const int n   = wid & 3;    // head (epilogue)
    const int h   = wid >> 2;   // half (epilogue)

    // XCD-chunked swizzle (bijective, 256 % 8 == 0)
    const int bid = blockIdx.y * 16 + blockIdx.x;
    const int swz = (bid & 7) * 32 + (bid >> 3);
    const int x0 = (swz & 15) * TW_;
    const int y0 = (swz >> 4) * TH_;
    const int b  = blockIdx.z;
    const float* mainb = mainp + ((size_t)b * H_) * W_ * C_;
    const float* refb  = refp  + ((size_t)b * H_) * W_ * C_;

    // ==== Fused wave-local phase: stage -> proj(4 heads) -> in-place write ====
    // wave 0..3: ref strips px [w*32, w*32+32); wave 4: ref tail px [128,144)
    // wave 5..6: main strips px [(w-5)*32, ...+32); wave 7: idle here.
    if (wid < 7) {
        const bool   isRef = (wid < 5);
        f16*         dst   = isRef ? abuf : mabuf;
        const float* gs    = isRef ? refb : mainb;
        const float* wsrc  = isRef ? wref : wmain;
        const int    pbase = isRef ? wid * 32 : (wid - 5) * 32;
        const int    nvalid = (wid == 4) ? 16 : 32;
        const int    nrounds = nvalid >> 2;          // 4 px per round

        // ---- stage own strip (coalesced: 16 lanes cover one pixel row) ----
        #pragma unroll
        for (int t = 0; t < 8; ++t) {
            if (t < nrounds) {
                int j  = t * 64 + l;
                int px = pbase + (j >> 4);
                int c4 = j & 15;
                int gy, gx; bool ok;
                if (isRef) {
                    int hy = div12(px), hx = px - hy * HWID;
                    gy = y0 + hy - 2; gx = x0 + hx - 2;
                    ok = ((unsigned)gy < (unsigned)H_) && ((unsigned)gx < (unsigned)W_);
                } else {
                    gy = y0 + (px >> 3); gx = x0 + (px & 7); ok = true;
                }
                float4 v = make_float4(0.f, 0.f, 0.f, 0.f);
                if (ok) v = *(const float4*)(gs + ((size_t)gy * W_ + gx) * C_ + c4 * 4);
                f16x4 h4 = {(f16)v.x, (f16)v.y, (f16)v.z, (f16)v.w};
                *(f16x4*)(dst + px * 64 + ((((c4 >> 1) ^ (px & 7)) << 3) | ((c4 & 1) << 2))) = h4;
            }
        }
        // wave-local RAW fence: staged writes visible before proj B reads
        asm volatile("s_waitcnt lgkmcnt(0)" ::: "memory");
        __builtin_amdgcn_sched_barrier(0);

        // ---- project both head-pairs (32x32x16, R12-verified layouts) ----
        f16x4 o0[4], o1[4];
        #pragma unroll
        for (int p2 = 0; p2 < 2; ++p2) {
            f16x8 A[4];
            {
                int rowA = l & 31;
                const float* w = wsrc + (p2 * 2 + (rowA >> 4)) * C_ * D_ + (rowA & 15);
                int kbase = (l >> 5) * 8;
                #pragma unroll
                for (int s = 0; s < 4; ++s) {
                    union { f16x8 v; f16 e[8]; } u;
                    #pragma unroll
                    for (int i = 0; i < 8; ++i)
                        u.e[i] = (f16)w[(s * 16 + kbase + i) * D_];
                    A[s] = u.v;
                }
            }
            int px = pbase + (l & 31);
            const f16* rp = dst + px * 64;
            f32x16 acc = {};
            #pragma unroll
            for (int s = 0; s < 4; ++s) {
                f16x8 Bv = *(const f16x8*)(rp + (((s * 2 + (l >> 5)) ^ (px & 7)) << 3));
                acc = __builtin_amdgcn_mfma_f32_32x32x16_f16(A[s], Bv, acc, 0, 0, 0);
            }
            f16x4* o = p2 ? o1 : o0;
            #pragma unroll
            for (int cc = 0; cc < 4; ++cc)
                o[cc] = f16x4{(f16)acc[4*cc], (f16)acc[4*cc+1],
                              (f16)acc[4*cc+2], (f16)acc[4*cc+3]};
        }
        // all B reads of this strip complete before in-place overwrite
        asm volatile("s_waitcnt lgkmcnt(0)" ::: "memory");
        __builtin_amdgcn_sched_barrier(0);

        if ((l & 31) < nvalid) {
            int px = pbase + (l & 31);
            int hi = l >> 5;
            #pragma unroll
            for (int p2 = 0; p2 < 2; ++p2) {
                const f16x4* o = p2 ? o1 : o0;
                #pragma unroll
                for (int cc = 0; cc < 4; ++cc) {
                    int c = (p2 * 2 + (cc >> 1)) * 2 + (cc & 1);   // 8-f16 chunk
                    *(f16x4*)(dst + px * 64 + (((c ^ (px & 7)) << 3) | (hi << 2))) = o[cc];
                }
            }
        }
    }
    __syncthreads();   // bar_mid: rbuf/qbuf globally ready

    // ==== Epilogue: byte-identical to R11 ====
    const int py  = l >> 3;
    const int pxx = l & 7;
    f16x8 q0 = *(const f16x8*)(mabuf + l * 64 + ((((n << 1) | 0) ^ (l & 7)) << 3));
    f16x8 q1 = *(const f16x8*)(mabuf + l * 64 + ((((n << 1) | 1) ^ (l & 7)) << 3));
    const f16x2* q2a = (const f16x2*)&q0;
    const f16x2* q2b = (const f16x2*)&q1;

    float lg[13];
    auto do_lg = [&](int idx, int k) {
        int ky = k / 5, kx = k % 5;              // compile-time
        int np = (py + ky) * 12 + pxx + kx;
        const f16* rp = abuf + np * 64;
        f16x8 r0 = *(const f16x8*)(rp + ((((n << 1) | 0) ^ (np & 7)) << 3));
        f16x8 r1 = *(const f16x8*)(rp + ((((n << 1) | 1) ^ (np & 7)) << 3));
        const f16x2* r2a = (const f16x2*)&r0;
        const f16x2* r2b = (const f16x2*)&r1;
        float a = 0.f;
        #pragma unroll
        for (int j = 0; j < 4; ++j) a = FDOT2(q2a[j], r2a[j], a);
        #pragma unroll
        for (int j = 0; j < 4; ++j) a = FDOT2(q2b[j], r2b[j], a);
        lg[idx] = a;
    };
    if (h == 0) {
        do_lg(0,0);  do_lg(1,1);  do_lg(2,2);  do_lg(3,3);  do_lg(4,4);
        do_lg(5,5);  do_lg(6,6);  do_lg(7,7);  do_lg(8,8);  do_lg(9,9);
        do_lg(10,10); do_lg(11,11); do_lg(12,12);
    } else {
        do_lg(0,13); do_lg(1,14); do_lg(2,15); do_lg(3,16); do_lg(4,17);
        do_lg(5,18); do_lg(6,19); do_lg(7,20); do_lg(8,21); do_lg(9,22);
        do_lg(10,23); do_lg(11,24);
        lg[12] = -1e30f;   // dead slot -> exp()=0
    }

    float mloc = lg[0];
    #pragma unroll
    for (int k = 1; k < 13; ++k) mloc = fmaxf(mloc, lg[k]);

    float s = 0.f;
    f16x2 pk[7];
    #pragma unroll
    for (int j = 0; j < 6; ++j) {
        float e0 = __expf(lg[2*j]   - mloc);
        float e1 = __expf(lg[2*j+1] - mloc);
        s += e0 + e1;
        pk[j] = f16x2{(f16)e0, (f16)e1};
    }
    {
        float e12 = __expf(lg[12] - mloc);
        s += e12;
        pk[6] = f16x2{(f16)e12, (f16)0.f};
    }
    msbuf[(h * 4 + n) * 64 + l] = make_float2(mloc, s);
    __syncthreads();   // bar4
    float2 o = msbuf[((1 - h) * 4 + n) * 64 + l];
    float m    = fmaxf(mloc, o.x);
    float sc   = __expf(mloc - m);
    float osc  = __expf(o.x  - m);
    float inv  = sc / (s * sc + o.y * osc);

    {
        float* dst = &xbuf[n * PSLAB + l * PSTRIDE + h * 13];
        #pragma unroll
        for (int j = 0; j < 6; ++j) {
            dst[2*j]     = (float)pk[j][0] * inv;
            dst[2*j + 1] = (float)pk[j][1] * inv;
        }
        if (h == 0) dst[12] = (float)pk[6][0] * inv;
    }
    __syncthreads();   // bar5

    for (int i = tid; i < TW_ * TH_ * KK_; i += 512) {
        int p2 = i / KK_;
        int k  = i - p2 * KK_;
        int off = p2 * PSTRIDE + k;
        float v = 0.25f * (xbuf[off] + xbuf[PSLAB + off] + xbuf[2 * PSLAB + off] + xbuf[3 * PSLAB + off]);
        out[(((size_t)b * H_ + (y0 + (p2 >> 3))) * W_ + (x0 + (p2 & 7))) * KK_ + k] = v;
    }
}

extern "C" void kernel_launch(void* const* d_in, const int* in_sizes, int n_in,
                              void* d_out, int out_size, void* d_ws, size_t ws_size,
                              hipStream_t stream) {
    const float* mainp = (const float*)d_in[0];
    const float* refp  = (const float*)d_in[1];
    const float* wmain = (const float*)d_in[2];
    const float* wref  = (const float*)d_in[3];
    float* outp = (float*)d_out;

    dim3 grid(W_ / TW_, H_ / TH_, B_);
    rl8mh13<<<grid, dim3(512), 0, stream>>>(mainp, refp, wmain, wref, outp);
}